// Round 23
// baseline (229.765 us; speedup 1.0000x reference)
//
#include <hip/hip_runtime.h>

#define IN_    16
#define HID_   50
#define T_     128
#define NCLS_  20
#define BPW_   16     // batches per wave = MFMA N; 1 wave per block
#define NTHR_  64
#define KP_    104    // slab row stride in halves (52 dw, 13x16B) -> conflict-free b128
#define KPW_   52

typedef _Float16 half8 __attribute__((ext_vector_type(8)));
typedef float    f32x4 __attribute__((ext_vector_type(4)));
typedef unsigned int u32;

#define L2E_ 1.4426950408889634f
__device__ __forceinline__ u32 pkh2(float a, float b) {
    union { u32 v; _Float16 h[2]; } p; p.h[0] = (_Float16)a; p.h[1] = (_Float16)b; return p.v;
}
#define MFMA(A, B, C) __builtin_amdgcn_mfma_f32_16x16x32_f16((A), (B), (C), 0, 0, 0)
// activation-domain helpers (weights/bias PRE-SCALED by -log2e / -2log2e)
#define SIGS(v)  __builtin_amdgcn_rcpf(1.0f + __builtin_amdgcn_exp2f(v))
#define TANHS(v) fmaf(2.0f, __builtin_amdgcn_rcpf(1.0f + __builtin_amdgcn_exp2f(v)), -1.0f)

#define REP13(OP) OP(0) OP(1) OP(2) OP(3) OP(4) OP(5) OP(6) OP(7) OP(8) OP(9) OP(10) OP(11) OP(12)

// A-fragment slice from GLOBAL. K layout: 0..15 = x rows (W_ih),
// 16..65 = h rows (W_hh), 66 = bias row, 67..95 = zero pad.
__device__ __forceinline__ half8 load_afrag(const float* __restrict__ W_ih,
                                            const float* __restrict__ W_hh,
                                            const float* __restrict__ b_ih,
                                            const float* __restrict__ b_hh,
                                            int s, int c, int q) {
    half8 r = {};
    const int u = s >> 2, kk = s & 3;
    if (u < HID_) {
        const float sc = (kk == 2) ? (-2.0f * L2E_) : (-L2E_);
        const int g = kk * HID_ + u;
        #pragma unroll
        for (int e = 0; e < 8; ++e) {
            const int k = c * 32 + q * 8 + e;
            float w = 0.f;
            if (k < IN_)                 w = W_ih[g * IN_ + k];
            else if (k < IN_ + HID_)     w = W_hh[g * HID_ + (k - IN_)];
            else if (k == IN_ + HID_)    w = b_ih[g] + b_hh[g];     // bias row
            r[e] = (_Float16)(w * sc);
        }
    }
    return r;
}

// ONE WAVE = ONE BLOCK = 16 batches, whole recurrence private -> ZERO barriers
// in the T-loop (same-wave DS ops are in-order; lgkmcnt handles visibility).
// waves_per_eu(1,2) caps the allocator's occupancy target -> 256-VGPR budget
// for the ~220-reg demand (39 A-frags + 13 c + B + misc), avoiding R5's
// occupancy-chase spill. Grid 512 -> 2 free-running waves/CU, no phase-lock.
__global__ __launch_bounds__(NTHR_)
__attribute__((amdgpu_waves_per_eu(1, 2)))
void lstm_wave(const float* __restrict__ x,
               const float* __restrict__ W_ih,
               const float* __restrict__ W_hh,
               const float* __restrict__ b_ih,
               const float* __restrict__ b_hh,
               const float* __restrict__ W_fc,
               const float* __restrict__ b_fc,
               float* __restrict__ out)
{
    // wave-private state slab: [batch][k]; k: 0..15 x, 16..65 h, 66 bias, 67..103 pad
    __shared__ __align__(16) _Float16 slab[BPW_ * KP_];   // 3.3 KB, single buffer

    const int lane = threadIdx.x;
    const int b0   = blockIdx.x * BPW_;
    const int q    = lane >> 4;
    const int m    = lane & 15;
    const int bcol = lane & 15;

    // ---- init slab: zeros; u32 33 of each row = bias half (1.0 at half 66)
    for (int i = lane; i < BPW_ * KPW_; i += NTHR_)
        ((u32*)slab)[i] = ((i % KPW_) == 33) ? 0x00003C00u : 0u;

    // ---- all 13 tiles' A-fragments -> registers (one time; ~156 VGPRs)
    #define DECLA(T) \
        half8 A##T##_0 = load_afrag(W_ih, W_hh, b_ih, b_hh, (T)*16 + m, 0, q); \
        half8 A##T##_1 = load_afrag(W_ih, W_hh, b_ih, b_hh, (T)*16 + m, 1, q); \
        half8 A##T##_2 = load_afrag(W_ih, W_hh, b_ih, b_hh, (T)*16 + m, 2, q);
    REP13(DECLA)
    #undef DECLA

    // c-state: ONE unit per lane per tile (C/D row = q*4+reg -> unit = T*4+q)
    #define DECLC(T) float c##T = 0.f;
    REP13(DECLC)
    #undef DECLC

    const int brow = bcol * KP_ + q * 8;       // B-frag half idx (chunk 0)
    const int hw   = bcol * KP_ + IN_ + q;     // h write base; +4*T per tile

    // ---- x mapping: 64 lanes = 16 batches x 4 feature-quads
    const int lb = lane >> 2, fq = lane & 3;
    const float* xq = x + (size_t)(b0 + lb) * (T_ * IN_) + 4 * fq;
    const int xo = lb * KPW_ + 2 * fq;         // u32 idx in slab

    // x(0) -> slab; x(1) -> regs
    {
        const float4 v = *(const float4*)xq;
        u32* d = (u32*)slab;
        d[xo] = pkh2(v.x, v.y); d[xo + 1] = pkh2(v.z, v.w);
    }
    float4 xr = *(const float4*)(xq + IN_);

    for (int t = 0; t < T_; ++t) {
        // read full state (t) into regs BEFORE any overwrite (same-wave DS order)
        const half8 B0 = *(const half8*)(slab + brow);
        const half8 B1 = *(const half8*)(slab + brow + 32);
        const half8 B2 = *(const half8*)(slab + brow + 64);

        // x(t+1) from regs into slab; prefetch x(t+2) (latency hides under tiles)
        if (t + 1 < T_) {
            u32* d = (u32*)slab;
            d[xo] = pkh2(xr.x, xr.y); d[xo + 1] = pkh2(xr.z, xr.w);
        }
        if (t + 2 < T_) xr = *(const float4*)(xq + (size_t)(t + 2) * IN_);

        const f32x4 Z = {0.f, 0.f, 0.f, 0.f};
        // 13 independent tile chains: 3 MFMA + 10 trans + c/h update each
        #define DOT(T) { \
            f32x4 C = MFMA(A##T##_0, B0, Z); \
            C = MFMA(A##T##_1, B1, C); \
            C = MFMA(A##T##_2, B2, C); \
            const float iv = SIGS(C[0]), fv = SIGS(C[1]); \
            const float gv = TANHS(C[2]), ov = SIGS(C[3]); \
            c##T = fmaf(fv, c##T, iv * gv); \
            const float hv = ov * TANHS(c##T * (-2.0f * L2E_)); \
            if ((T) * 4 + q < HID_) slab[hw + (T) * 4] = (_Float16)hv; }
        REP13(DOT)
        #undef DOT
        // no barrier: next iteration's B-reads are ordered after these writes
        // by the wave's in-order DS pipeline + compiler lgkmcnt.
    }

    // ---- FC head: this wave's 16 batches x 20 classes (5 outputs/lane)
    for (int p = lane; p < BPW_ * NCLS_; p += NTHR_) {
        const int b  = p / NCLS_;
        const int cl = p - b * NCLS_;
        float acc = b_fc[cl];
        #pragma unroll
        for (int j = 0; j < HID_; ++j) {
            const float hv = fmaxf((float)slab[b * KP_ + IN_ + j], 0.0f);  // relu
            acc = fmaf(hv, W_fc[cl * HID_ + j], acc);
        }
        out[(size_t)(b0 + b) * NCLS_ + cl] = acc;
    }
}

extern "C" void kernel_launch(void* const* d_in, const int* in_sizes, int n_in,
                              void* d_out, int out_size, void* d_ws, size_t ws_size,
                              hipStream_t stream) {
    const float* x    = (const float*)d_in[0];
    const float* W_ih = (const float*)d_in[1];
    const float* W_hh = (const float*)d_in[2];
    const float* b_ih = (const float*)d_in[3];
    const float* b_hh = (const float*)d_in[4];
    const float* W_fc = (const float*)d_in[5];
    const float* b_fc = (const float*)d_in[6];
    float* out = (float*)d_out;

    const int B = in_sizes[0] / (T_ * IN_);   // 8192
    dim3 grid(B / BPW_), block(NTHR_);        // 512 one-wave blocks
    hipLaunchKernelGGL(lstm_wave, grid, block, 0, stream,
                       x, W_ih, W_hh, b_ih, b_hh, W_fc, b_fc, out);
}

// Round 24
// 90.628 us; speedup vs baseline: 2.5353x; 2.5353x over previous
//
#include <hip/hip_runtime.h>

#define IN_    16
#define HID_   50
#define T_     128
#define NCLS_  20
#define BPB_   16     // batches per block = MFMA N (full; no garbage lanes)
#define NTHR_  320    // 5 waves: 4 compute (3 M-tiles each) + 1 loader(+tile 12)
#define KP_    104    // state row stride in halves = 52 dwords (4*13) -> conflict-free b128
#define KPW_   52     // stride in u32

typedef _Float16 half8 __attribute__((ext_vector_type(8)));
typedef float    f32x4 __attribute__((ext_vector_type(4)));
typedef unsigned int u32;

#define L2E_ 1.4426950408889634f
__device__ __forceinline__ u32 pkh2(float a, float b) {
    union { u32 v; _Float16 h[2]; } p; p.h[0] = (_Float16)a; p.h[1] = (_Float16)b; return p.v;
}
#define MFMA(A, B, C) __builtin_amdgcn_mfma_f32_16x16x32_f16((A), (B), (C), 0, 0, 0)
// activation-domain helpers (weights/bias PRE-SCALED by -log2e / -2log2e)
#define SIGS(v)  __builtin_amdgcn_rcpf(1.0f + __builtin_amdgcn_exp2f(v))
#define TANHS(v) fmaf(2.0f, __builtin_amdgcn_rcpf(1.0f + __builtin_amdgcn_exp2f(v)), -1.0f)

// A-fragment slice from GLOBAL. K layout: 0..15 = x rows (W_ih),
// 16..65 = h rows (W_hh), 66 = bias row, 67..95 = zero pad.
__device__ __forceinline__ half8 load_afrag(const float* __restrict__ W_ih,
                                            const float* __restrict__ W_hh,
                                            const float* __restrict__ b_ih,
                                            const float* __restrict__ b_hh,
                                            int s, int c, int q) {
    half8 r = {};
    const int u = s >> 2, kk = s & 3;
    if (u < HID_) {
        const float sc = (kk == 2) ? (-2.0f * L2E_) : (-L2E_);
        const int g = kk * HID_ + u;
        #pragma unroll
        for (int e = 0; e < 8; ++e) {
            const int k = c * 32 + q * 8 + e;
            float w = 0.f;
            if (k < IN_)                 w = W_ih[g * IN_ + k];
            else if (k < IN_ + HID_)     w = W_hh[g * HID_ + (k - IN_)];
            else if (k == IN_ + HID_)    w = b_ih[g] + b_hh[g];     // bias row
            r[e] = (_Float16)(w * sc);
        }
    }
    return r;
}

// R22 (90.6us) with ONE change: the loader wave issues its global x-load and
// LDS x-write at the TOP of its step, so its own tile-12 compute hides the
// load latency before the barrier's per-wave vmcnt(0) drain (previously the
// load was issued immediately before __syncthreads -> full latency exposed,
// loader = straggler of every barrier period).
__global__ __launch_bounds__(NTHR_, 6)
void lstm_mfma(const float* __restrict__ x,
               const float* __restrict__ W_ih,
               const float* __restrict__ W_hh,
               const float* __restrict__ b_ih,
               const float* __restrict__ b_hh,
               const float* __restrict__ W_fc,
               const float* __restrict__ b_fc,
               float* __restrict__ out)
{
    // ONLY state in LDS: st[buf][batch*KP_ + k]
    __shared__ __align__(16) _Float16 st[2][BPB_ * KP_];   // 6.8 KB

    const int tid  = threadIdx.x;
    const int lane = tid & 63;
    const int wv   = tid >> 6;          // 0..4
    const int b0   = blockIdx.x * BPB_;
    const bool comp = (wv < 4);         // waves 0-3: 3 tiles; wave 4: loader + tile 12

    // ---- init state: zeros; half 66 of each row = 1.0 (bias row, BOTH buffers,
    //      never rewritten). h(0)=0; pad rows stay 0 forever.
    for (int idx = tid; idx < 2 * BPB_ * KPW_; idx += NTHR_)
        ((u32*)st)[idx] = ((idx % KPW_) == 33) ? 0x00003C00u : 0u;  // halves 66,67

    const int q    = lane >> 4;
    const int bcol = lane & 15;
    const int brow = bcol * KP_ + q * 8;           // B-frag half index (chunk 0)

    // ---- A-fragments from global -> regs (one time).
    //      waves 0-3: tiles 3wv..3wv+2 ; wave 4: tile 12.
    const int t0 = comp ? (3 * wv) : 12;
    const int s0 = t0 * 16 + (lane & 15);
    half8 A00 = load_afrag(W_ih, W_hh, b_ih, b_hh, s0, 0, q);
    half8 A01 = load_afrag(W_ih, W_hh, b_ih, b_hh, s0, 1, q);
    half8 A02 = load_afrag(W_ih, W_hh, b_ih, b_hh, s0, 2, q);
    half8 A10 = {}, A11 = {}, A12 = {}, A20 = {}, A21 = {}, A22 = {};
    if (comp) {
        A10 = load_afrag(W_ih, W_hh, b_ih, b_hh, s0 + 16, 0, q);
        A11 = load_afrag(W_ih, W_hh, b_ih, b_hh, s0 + 16, 1, q);
        A12 = load_afrag(W_ih, W_hh, b_ih, b_hh, s0 + 16, 2, q);
        A20 = load_afrag(W_ih, W_hh, b_ih, b_hh, s0 + 32, 0, q);
        A21 = load_afrag(W_ih, W_hh, b_ih, b_hh, s0 + 32, 1, q);
        A22 = load_afrag(W_ih, W_hh, b_ih, b_hh, s0 + 32, 2, q);
    }

    // per-lane units (C/D: col=lane&15, row=q*4+reg -> unit = tile*4+q)
    const int u0 = t0 * 4 + q;                     // wave4: 48..51 (48,49 real)
    const int u1 = u0 + 4;
    const int u2 = u0 + 8;
    float c0_ = 0.f, c1_ = 0.f, c2_ = 0.f;

    const int hrow0 = bcol * KP_ + IN_ + u0;
    const int hrow1 = bcol * KP_ + IN_ + u1;
    const int hrow2 = bcol * KP_ + IN_ + u2;

    // ---- loader mapping (wave 4): 64 lanes = 16 batches x 4 feature-quads
    const int lb = lane >> 2, fq = lane & 3;
    const float* xq = x + (size_t)(b0 + lb) * (T_ * IN_) + 4 * fq;
    const int xo = lb * KPW_ + 2 * fq;             // u32 index

    float4 xr = {0.f, 0.f, 0.f, 0.f};
    __syncthreads();                               // init visible
    if (!comp) {                                   // x(0) -> LDS, x(1) -> regs
        const float4 v = *(const float4*)xq;
        u32* d = (u32*)st[0];
        d[xo] = pkh2(v.x, v.y); d[xo + 1] = pkh2(v.z, v.w);
        xr = *(const float4*)(xq + IN_);
    }
    __syncthreads();                               // x(0) ready

    for (int t = 0; t < T_; ++t) {
        const _Float16* sc = st[t & 1];
        _Float16*       sn = st[(t & 1) ^ 1];

        const half8 B0 = *(const half8*)(sc + brow);
        const half8 B1 = *(const half8*)(sc + brow + 32);
        const half8 B2 = *(const half8*)(sc + brow + 64);
        const f32x4 Z = {0.f, 0.f, 0.f, 0.f};

        if (comp) {
            __builtin_amdgcn_s_setprio(1);         // T5: favor compute waves
            // 3 independent C-chains (ILP): 9 MFMA, B-frags shared
            f32x4 C0 = MFMA(A00, B0, Z);
            f32x4 C1 = MFMA(A10, B0, Z);
            f32x4 C2 = MFMA(A20, B0, Z);
            C0 = MFMA(A01, B1, C0);
            C1 = MFMA(A11, B1, C1);
            C2 = MFMA(A21, B1, C2);
            C0 = MFMA(A02, B2, C0);    // chunk 2 carries h-tails + bias row
            C1 = MFMA(A12, B2, C1);
            C2 = MFMA(A22, B2, C2);

            {   const float iv = SIGS(C0[0]), fv = SIGS(C0[1]);
                const float gv = TANHS(C0[2]), ov = SIGS(C0[3]);
                c0_ = fmaf(fv, c0_, iv * gv);
                sn[hrow0] = (_Float16)(ov * TANHS(c0_ * (-2.0f * L2E_))); }
            {   const float iv = SIGS(C1[0]), fv = SIGS(C1[1]);
                const float gv = TANHS(C1[2]), ov = SIGS(C1[3]);
                c1_ = fmaf(fv, c1_, iv * gv);
                sn[hrow1] = (_Float16)(ov * TANHS(c1_ * (-2.0f * L2E_))); }
            {   const float iv = SIGS(C2[0]), fv = SIGS(C2[1]);
                const float gv = TANHS(C2[2]), ov = SIGS(C2[3]);
                c2_ = fmaf(fv, c2_, iv * gv);
                sn[hrow2] = (_Float16)(ov * TANHS(c2_ * (-2.0f * L2E_))); }
            __builtin_amdgcn_s_setprio(0);
        } else {
            // LOADER FIRST: issue global x(t+2) load + LDS x(t+1) write at the
            // TOP, so tile-12 compute below hides the latency before the
            // barrier's vmcnt(0) drain.
            float4 xn = {0.f, 0.f, 0.f, 0.f};
            if (t + 2 < T_) xn = *(const float4*)(xq + (size_t)(t + 2) * IN_);
            if (t + 1 < T_) {
                u32* d = (u32*)sn;
                d[xo] = pkh2(xr.x, xr.y); d[xo + 1] = pkh2(xr.z, xr.w);
            }
            // tile 12 (units 48,49 real)
            f32x4 C0 = MFMA(A00, B0, Z);
            C0 = MFMA(A01, B1, C0);
            C0 = MFMA(A02, B2, C0);
            const float iv = SIGS(C0[0]), fv = SIGS(C0[1]);
            const float gv = TANHS(C0[2]), ov = SIGS(C0[3]);
            c0_ = fmaf(fv, c0_, iv * gv);
            if (u0 < HID_) sn[hrow0] = (_Float16)(ov * TANHS(c0_ * (-2.0f * L2E_)));
            xr = xn;                               // consume next step
        }
        __syncthreads();               // ONE barrier per step (5 waves)
    }

    // final h in st[0] (t=127 wrote nxt=0), fp16 rows 16..65
    const _Float16* hf = st[0];

    // ---- FC head: 16 batches x 20 classes = 320 threads (exact)
    {
        const int b  = tid / NCLS_;
        const int cl = tid - b * NCLS_;
        float acc = b_fc[cl];
        #pragma unroll
        for (int j = 0; j < HID_; ++j) {
            const float hv = fmaxf((float)hf[b * KP_ + IN_ + j], 0.0f);  // relu
            acc = fmaf(hv, W_fc[cl * HID_ + j], acc);
        }
        out[(size_t)(b0 + b) * NCLS_ + cl] = acc;
    }
}

extern "C" void kernel_launch(void* const* d_in, const int* in_sizes, int n_in,
                              void* d_out, int out_size, void* d_ws, size_t ws_size,
                              hipStream_t stream) {
    const float* x    = (const float*)d_in[0];
    const float* W_ih = (const float*)d_in[1];
    const float* W_hh = (const float*)d_in[2];
    const float* b_ih = (const float*)d_in[3];
    const float* b_hh = (const float*)d_in[4];
    const float* W_fc = (const float*)d_in[5];
    const float* b_fc = (const float*)d_in[6];
    float* out = (float*)d_out;

    const int B = in_sizes[0] / (T_ * IN_);   // 8192
    dim3 grid(B / BPB_), block(NTHR_);
    hipLaunchKernelGGL(lstm_mfma, grid, block, 0, stream,
                       x, W_ih, W_hh, b_ih, b_hh, W_fc, b_fc, out);
}

// Round 25
// 85.572 us; speedup vs baseline: 2.6851x; 1.0591x over previous
//
#include <hip/hip_runtime.h>

#define IN_    16
#define HID_   50
#define T_     128
#define NCLS_  20
#define BPB_   16     // batches per block = MFMA N (full; no garbage lanes)
#define NTHR_  320    // 5 waves: 4 compute (3 M-tiles each) + 1 loader(+tile 12)
#define KP_    104    // state row stride in halves = 52 dwords (4*13) -> conflict-free b128
#define KPW_   52     // stride in u32

typedef _Float16 half8 __attribute__((ext_vector_type(8)));
typedef float    f32x4 __attribute__((ext_vector_type(4)));
typedef unsigned int u32;

#define L2E_ 1.4426950408889634f
__device__ __forceinline__ u32 pkh2(float a, float b) {
    union { u32 v; _Float16 h[2]; } p; p.h[0] = (_Float16)a; p.h[1] = (_Float16)b; return p.v;
}
#define MFMA(A, B, C) __builtin_amdgcn_mfma_f32_16x16x32_f16((A), (B), (C), 0, 0, 0)
#define EXP2(v) __builtin_amdgcn_exp2f(v)
#define RCP(v)  __builtin_amdgcn_rcpf(v)
// shared-reciprocal activation pair: inputs are exp2 of PRE-SCALED pre-acts.
// sig_from(eA) * tanh_from(eB) = (1-eB) / ((1+eA)(1+eB)) — ONE rcp for two
// activations (cuts the tile-chain trans count 10 -> 8).
__device__ __forceinline__ float act_pair(float eA, float eB) {
    return (1.0f - eB) * RCP((1.0f + eA) * (1.0f + eB));
}

// A-fragment slice from GLOBAL. K layout: 0..15 = x rows (W_ih),
// 16..65 = h rows (W_hh), 66 = bias row, 67..95 = zero pad.
__device__ __forceinline__ half8 load_afrag(const float* __restrict__ W_ih,
                                            const float* __restrict__ W_hh,
                                            const float* __restrict__ b_ih,
                                            const float* __restrict__ b_hh,
                                            int s, int c, int q) {
    half8 r = {};
    const int u = s >> 2, kk = s & 3;
    if (u < HID_) {
        const float sc = (kk == 2) ? (-2.0f * L2E_) : (-L2E_);
        const int g = kk * HID_ + u;
        #pragma unroll
        for (int e = 0; e < 8; ++e) {
            const int k = c * 32 + q * 8 + e;
            float w = 0.f;
            if (k < IN_)                 w = W_ih[g * IN_ + k];
            else if (k < IN_ + HID_)     w = W_hh[g * HID_ + (k - IN_)];
            else if (k == IN_ + HID_)    w = b_ih[g] + b_hh[g];     // bias row
            r[e] = (_Float16)(w * sc);
        }
    }
    return r;
}

// activation block with shared-rcp pairs: 5 exp2 + 3 rcp (was 5 exp2 + 5 rcp)
#define ACT_UPDATE(C, cvar, hrow) do {                                   \
    const float ei = EXP2((C)[0]);                                       \
    const float ef = EXP2((C)[1]);                                       \
    const float eg = EXP2((C)[2]);                                       \
    const float eo = EXP2((C)[3]);                                       \
    const float fv = RCP(1.0f + ef);                                     \
    const float ig = act_pair(ei, eg);                                   \
    cvar = fmaf(fv, cvar, ig);                                           \
    const float e2c = EXP2(cvar * (-2.0f * L2E_));                       \
    sn[hrow] = (_Float16)act_pair(eo, e2c);                              \
} while (0)

// R24 structure (90.6us best) + shared-rcp activations.
__global__ __launch_bounds__(NTHR_, 6)
void lstm_mfma(const float* __restrict__ x,
               const float* __restrict__ W_ih,
               const float* __restrict__ W_hh,
               const float* __restrict__ b_ih,
               const float* __restrict__ b_hh,
               const float* __restrict__ W_fc,
               const float* __restrict__ b_fc,
               float* __restrict__ out)
{
    // ONLY state in LDS: st[buf][batch*KP_ + k]
    __shared__ __align__(16) _Float16 st[2][BPB_ * KP_];   // 6.8 KB

    const int tid  = threadIdx.x;
    const int lane = tid & 63;
    const int wv   = tid >> 6;          // 0..4
    const int b0   = blockIdx.x * BPB_;
    const bool comp = (wv < 4);         // waves 0-3: 3 tiles; wave 4: loader + tile 12

    // ---- init state: zeros; half 66 of each row = 1.0 (bias row, BOTH buffers,
    //      never rewritten). h(0)=0; pad rows stay 0 forever.
    for (int idx = tid; idx < 2 * BPB_ * KPW_; idx += NTHR_)
        ((u32*)st)[idx] = ((idx % KPW_) == 33) ? 0x00003C00u : 0u;  // halves 66,67

    const int q    = lane >> 4;
    const int bcol = lane & 15;
    const int brow = bcol * KP_ + q * 8;           // B-frag half index (chunk 0)

    // ---- A-fragments from global -> regs (one time).
    //      waves 0-3: tiles 3wv..3wv+2 ; wave 4: tile 12.
    const int t0 = comp ? (3 * wv) : 12;
    const int s0 = t0 * 16 + (lane & 15);
    half8 A00 = load_afrag(W_ih, W_hh, b_ih, b_hh, s0, 0, q);
    half8 A01 = load_afrag(W_ih, W_hh, b_ih, b_hh, s0, 1, q);
    half8 A02 = load_afrag(W_ih, W_hh, b_ih, b_hh, s0, 2, q);
    half8 A10 = {}, A11 = {}, A12 = {}, A20 = {}, A21 = {}, A22 = {};
    if (comp) {
        A10 = load_afrag(W_ih, W_hh, b_ih, b_hh, s0 + 16, 0, q);
        A11 = load_afrag(W_ih, W_hh, b_ih, b_hh, s0 + 16, 1, q);
        A12 = load_afrag(W_ih, W_hh, b_ih, b_hh, s0 + 16, 2, q);
        A20 = load_afrag(W_ih, W_hh, b_ih, b_hh, s0 + 32, 0, q);
        A21 = load_afrag(W_ih, W_hh, b_ih, b_hh, s0 + 32, 1, q);
        A22 = load_afrag(W_ih, W_hh, b_ih, b_hh, s0 + 32, 2, q);
    }

    // per-lane units (C/D: col=lane&15, row=q*4+reg -> unit = tile*4+q)
    const int u0 = t0 * 4 + q;                     // wave4: 48..51 (48,49 real)
    const int u1 = u0 + 4;
    const int u2 = u0 + 8;
    float c0_ = 0.f, c1_ = 0.f, c2_ = 0.f;

    const int hrow0 = bcol * KP_ + IN_ + u0;
    const int hrow1 = bcol * KP_ + IN_ + u1;
    const int hrow2 = bcol * KP_ + IN_ + u2;

    // ---- loader mapping (wave 4): 64 lanes = 16 batches x 4 feature-quads
    const int lb = lane >> 2, fq = lane & 3;
    const float* xq = x + (size_t)(b0 + lb) * (T_ * IN_) + 4 * fq;
    const int xo = lb * KPW_ + 2 * fq;             // u32 index

    float4 xr = {0.f, 0.f, 0.f, 0.f};
    __syncthreads();                               // init visible
    if (!comp) {                                   // x(0) -> LDS, x(1) -> regs
        const float4 v = *(const float4*)xq;
        u32* d = (u32*)st[0];
        d[xo] = pkh2(v.x, v.y); d[xo + 1] = pkh2(v.z, v.w);
        xr = *(const float4*)(xq + IN_);
    }
    __syncthreads();                               // x(0) ready

    for (int t = 0; t < T_; ++t) {
        const _Float16* sc = st[t & 1];
        _Float16*       sn = st[(t & 1) ^ 1];

        const half8 B0 = *(const half8*)(sc + brow);
        const half8 B1 = *(const half8*)(sc + brow + 32);
        const half8 B2 = *(const half8*)(sc + brow + 64);
        const f32x4 Z = {0.f, 0.f, 0.f, 0.f};

        if (comp) {
            __builtin_amdgcn_s_setprio(1);         // T5: favor compute waves
            // 3 independent C-chains (ILP): 9 MFMA, B-frags shared
            f32x4 C0 = MFMA(A00, B0, Z);
            f32x4 C1 = MFMA(A10, B0, Z);
            f32x4 C2 = MFMA(A20, B0, Z);
            C0 = MFMA(A01, B1, C0);
            C1 = MFMA(A11, B1, C1);
            C2 = MFMA(A21, B1, C2);
            C0 = MFMA(A02, B2, C0);    // chunk 2 carries h-tails + bias row
            C1 = MFMA(A12, B2, C1);
            C2 = MFMA(A22, B2, C2);

            ACT_UPDATE(C0, c0_, hrow0);
            ACT_UPDATE(C1, c1_, hrow1);
            ACT_UPDATE(C2, c2_, hrow2);
            __builtin_amdgcn_s_setprio(0);
        } else {
            // loader first: global x(t+2) + LDS x(t+1) at the top; tile-12
            // compute hides the latency before the barrier drain.
            float4 xn = {0.f, 0.f, 0.f, 0.f};
            if (t + 2 < T_) xn = *(const float4*)(xq + (size_t)(t + 2) * IN_);
            if (t + 1 < T_) {
                u32* d = (u32*)sn;
                d[xo] = pkh2(xr.x, xr.y); d[xo + 1] = pkh2(xr.z, xr.w);
            }
            // tile 12 (units 48,49 real)
            f32x4 C0 = MFMA(A00, B0, Z);
            C0 = MFMA(A01, B1, C0);
            C0 = MFMA(A02, B2, C0);
            if (u0 < HID_) {
                ACT_UPDATE(C0, c0_, hrow0);
            }
            xr = xn;                               // consume next step
        }
        __syncthreads();               // ONE barrier per step (5 waves)
    }

    // final h in st[0] (t=127 wrote nxt=0), fp16 rows 16..65
    const _Float16* hf = st[0];

    // ---- FC head: 16 batches x 20 classes = 320 threads (exact)
    {
        const int b  = tid / NCLS_;
        const int cl = tid - b * NCLS_;
        float acc = b_fc[cl];
        #pragma unroll
        for (int j = 0; j < HID_; ++j) {
            const float hv = fmaxf((float)hf[b * KP_ + IN_ + j], 0.0f);  // relu
            acc = fmaf(hv, W_fc[cl * HID_ + j], acc);
        }
        out[(size_t)(b0 + b) * NCLS_ + cl] = acc;
    }
}

extern "C" void kernel_launch(void* const* d_in, const int* in_sizes, int n_in,
                              void* d_out, int out_size, void* d_ws, size_t ws_size,
                              hipStream_t stream) {
    const float* x    = (const float*)d_in[0];
    const float* W_ih = (const float*)d_in[1];
    const float* W_hh = (const float*)d_in[2];
    const float* b_ih = (const float*)d_in[3];
    const float* b_hh = (const float*)d_in[4];
    const float* W_fc = (const float*)d_in[5];
    const float* b_fc = (const float*)d_in[6];
    float* out = (float*)d_out;

    const int B = in_sizes[0] / (T_ * IN_);   // 8192
    dim3 grid(B / BPB_), block(NTHR_);
    hipLaunchKernelGGL(lstm_mfma, grid, block, 0, stream,
                       x, W_ih, W_hh, b_ih, b_hh, W_fc, b_fc, out);
}

// Round 26
// 85.101 us; speedup vs baseline: 2.6999x; 1.0055x over previous
//
#include <hip/hip_runtime.h>

#define IN_    16
#define HID_   50
#define T_     128
#define NCLS_  20
#define BPB_   16     // batches per block = MFMA N (full; no garbage lanes)
#define NTHR_  320    // 5 waves: 4 compute (3 M-tiles each) + 1 loader(+tile 12)
#define KP_    104    // state row stride in halves = 52 dwords (4*13) -> conflict-free b128
#define KPW_   52     // stride in u32

typedef _Float16 half8 __attribute__((ext_vector_type(8)));
typedef float    f32x4 __attribute__((ext_vector_type(4)));
typedef unsigned int u32;

#define L2E_ 1.4426950408889634f
__device__ __forceinline__ u32 pkh2(float a, float b) {
    union { u32 v; _Float16 h[2]; } p; p.h[0] = (_Float16)a; p.h[1] = (_Float16)b; return p.v;
}
#define MFMA(A, B, C) __builtin_amdgcn_mfma_f32_16x16x32_f16((A), (B), (C), 0, 0, 0)
#define EXP2(v) __builtin_amdgcn_exp2f(v)
#define RCP(v)  __builtin_amdgcn_rcpf(v)

// A-fragment slice from GLOBAL. K layout: 0..15 = x rows (W_ih),
// 16..65 = h rows (W_hh), 66 = bias row, 67..95 = zero pad.
__device__ __forceinline__ half8 load_afrag(const float* __restrict__ W_ih,
                                            const float* __restrict__ W_hh,
                                            const float* __restrict__ b_ih,
                                            const float* __restrict__ b_hh,
                                            int s, int c, int q) {
    half8 r = {};
    const int u = s >> 2, kk = s & 3;
    if (u < HID_) {
        const float sc = (kk == 2) ? (-2.0f * L2E_) : (-L2E_);
        const int g = kk * HID_ + u;
        #pragma unroll
        for (int e = 0; e < 8; ++e) {
            const int k = c * 32 + q * 8 + e;
            float w = 0.f;
            if (k < IN_)                 w = W_ih[g * IN_ + k];
            else if (k < IN_ + HID_)     w = W_hh[g * HID_ + (k - IN_)];
            else if (k == IN_ + HID_)    w = b_ih[g] + b_hh[g];     // bias row
            r[e] = (_Float16)(w * sc);
        }
    }
    return r;
}

// activation block, 5 exp2 + 2 rcp (was 5+3 in R25, 5+5 originally):
//   c' = c/(1+ef) + (1-eg)/((1+ei)(1+eg))  ==  [c*pig + (1-eg)*pf] / (pf*pig)
//   h  = (1-e2c) / ((1+eo)(1+e2c))         (sig(o)*tanh(c'), shared rcp)
#define ACT_UPDATE(C, cvar, hrow) do {                                   \
    const float ei = EXP2((C)[0]);                                       \
    const float ef = EXP2((C)[1]);                                       \
    const float eg = EXP2((C)[2]);                                       \
    const float eo = EXP2((C)[3]);                                       \
    const float pig = (1.0f + ei) * (1.0f + eg);                         \
    const float pf  = 1.0f + ef;                                         \
    const float num = fmaf(cvar, pig, (1.0f - eg) * pf);                 \
    cvar = num * RCP(pf * pig);                                          \
    const float e2c = EXP2(cvar * (-2.0f * L2E_));                       \
    sn[hrow] = (_Float16)((1.0f - e2c) * RCP((1.0f + eo) * (1.0f + e2c))); \
} while (0)

// R25 structure (85.6us best) + common-denominator c-update (one fewer rcp
// on the per-step serial chain).
__global__ __launch_bounds__(NTHR_, 6)
void lstm_mfma(const float* __restrict__ x,
               const float* __restrict__ W_ih,
               const float* __restrict__ W_hh,
               const float* __restrict__ b_ih,
               const float* __restrict__ b_hh,
               const float* __restrict__ W_fc,
               const float* __restrict__ b_fc,
               float* __restrict__ out)
{
    // ONLY state in LDS: st[buf][batch*KP_ + k]
    __shared__ __align__(16) _Float16 st[2][BPB_ * KP_];   // 6.8 KB

    const int tid  = threadIdx.x;
    const int lane = tid & 63;
    const int wv   = tid >> 6;          // 0..4
    const int b0   = blockIdx.x * BPB_;
    const bool comp = (wv < 4);         // waves 0-3: 3 tiles; wave 4: loader + tile 12

    // ---- init state: zeros; half 66 of each row = 1.0 (bias row, BOTH buffers,
    //      never rewritten). h(0)=0; pad rows stay 0 forever.
    for (int idx = tid; idx < 2 * BPB_ * KPW_; idx += NTHR_)
        ((u32*)st)[idx] = ((idx % KPW_) == 33) ? 0x00003C00u : 0u;  // halves 66,67

    const int q    = lane >> 4;
    const int bcol = lane & 15;
    const int brow = bcol * KP_ + q * 8;           // B-frag half index (chunk 0)

    // ---- A-fragments from global -> regs (one time).
    //      waves 0-3: tiles 3wv..3wv+2 ; wave 4: tile 12.
    const int t0 = comp ? (3 * wv) : 12;
    const int s0 = t0 * 16 + (lane & 15);
    half8 A00 = load_afrag(W_ih, W_hh, b_ih, b_hh, s0, 0, q);
    half8 A01 = load_afrag(W_ih, W_hh, b_ih, b_hh, s0, 1, q);
    half8 A02 = load_afrag(W_ih, W_hh, b_ih, b_hh, s0, 2, q);
    half8 A10 = {}, A11 = {}, A12 = {}, A20 = {}, A21 = {}, A22 = {};
    if (comp) {
        A10 = load_afrag(W_ih, W_hh, b_ih, b_hh, s0 + 16, 0, q);
        A11 = load_afrag(W_ih, W_hh, b_ih, b_hh, s0 + 16, 1, q);
        A12 = load_afrag(W_ih, W_hh, b_ih, b_hh, s0 + 16, 2, q);
        A20 = load_afrag(W_ih, W_hh, b_ih, b_hh, s0 + 32, 0, q);
        A21 = load_afrag(W_ih, W_hh, b_ih, b_hh, s0 + 32, 1, q);
        A22 = load_afrag(W_ih, W_hh, b_ih, b_hh, s0 + 32, 2, q);
    }

    // per-lane units (C/D: col=lane&15, row=q*4+reg -> unit = tile*4+q)
    const int u0 = t0 * 4 + q;                     // wave4: 48..51 (48,49 real)
    const int u1 = u0 + 4;
    const int u2 = u0 + 8;
    float c0_ = 0.f, c1_ = 0.f, c2_ = 0.f;

    const int hrow0 = bcol * KP_ + IN_ + u0;
    const int hrow1 = bcol * KP_ + IN_ + u1;
    const int hrow2 = bcol * KP_ + IN_ + u2;

    // ---- loader mapping (wave 4): 64 lanes = 16 batches x 4 feature-quads
    const int lb = lane >> 2, fq = lane & 3;
    const float* xq = x + (size_t)(b0 + lb) * (T_ * IN_) + 4 * fq;
    const int xo = lb * KPW_ + 2 * fq;             // u32 index

    float4 xr = {0.f, 0.f, 0.f, 0.f};
    __syncthreads();                               // init visible
    if (!comp) {                                   // x(0) -> LDS, x(1) -> regs
        const float4 v = *(const float4*)xq;
        u32* d = (u32*)st[0];
        d[xo] = pkh2(v.x, v.y); d[xo + 1] = pkh2(v.z, v.w);
        xr = *(const float4*)(xq + IN_);
    }
    __syncthreads();                               // x(0) ready

    for (int t = 0; t < T_; ++t) {
        const _Float16* sc = st[t & 1];
        _Float16*       sn = st[(t & 1) ^ 1];

        const half8 B0 = *(const half8*)(sc + brow);
        const half8 B1 = *(const half8*)(sc + brow + 32);
        const half8 B2 = *(const half8*)(sc + brow + 64);
        const f32x4 Z = {0.f, 0.f, 0.f, 0.f};

        if (comp) {
            __builtin_amdgcn_s_setprio(1);         // T5: favor compute waves
            // 3 independent C-chains (ILP): 9 MFMA, B-frags shared
            f32x4 C0 = MFMA(A00, B0, Z);
            f32x4 C1 = MFMA(A10, B0, Z);
            f32x4 C2 = MFMA(A20, B0, Z);
            C0 = MFMA(A01, B1, C0);
            C1 = MFMA(A11, B1, C1);
            C2 = MFMA(A21, B1, C2);
            C0 = MFMA(A02, B2, C0);    // chunk 2 carries h-tails + bias row
            C1 = MFMA(A12, B2, C1);
            C2 = MFMA(A22, B2, C2);

            ACT_UPDATE(C0, c0_, hrow0);
            ACT_UPDATE(C1, c1_, hrow1);
            ACT_UPDATE(C2, c2_, hrow2);
            __builtin_amdgcn_s_setprio(0);
        } else {
            // loader first: global x(t+2) + LDS x(t+1) at the top; tile-12
            // compute hides the latency before the barrier drain.
            float4 xn = {0.f, 0.f, 0.f, 0.f};
            if (t + 2 < T_) xn = *(const float4*)(xq + (size_t)(t + 2) * IN_);
            if (t + 1 < T_) {
                u32* d = (u32*)sn;
                d[xo] = pkh2(xr.x, xr.y); d[xo + 1] = pkh2(xr.z, xr.w);
            }
            // tile 12 (units 48,49 real)
            f32x4 C0 = MFMA(A00, B0, Z);
            C0 = MFMA(A01, B1, C0);
            C0 = MFMA(A02, B2, C0);
            if (u0 < HID_) {
                ACT_UPDATE(C0, c0_, hrow0);
            }
            xr = xn;                               // consume next step
        }
        __syncthreads();               // ONE barrier per step (5 waves)
    }

    // final h in st[0] (t=127 wrote nxt=0), fp16 rows 16..65
    const _Float16* hf = st[0];

    // ---- FC head: 16 batches x 20 classes = 320 threads (exact)
    {
        const int b  = tid / NCLS_;
        const int cl = tid - b * NCLS_;
        float acc = b_fc[cl];
        #pragma unroll
        for (int j = 0; j < HID_; ++j) {
            const float hv = fmaxf((float)hf[b * KP_ + IN_ + j], 0.0f);  // relu
            acc = fmaf(hv, W_fc[cl * HID_ + j], acc);
        }
        out[(size_t)(b0 + b) * NCLS_ + cl] = acc;
    }
}

extern "C" void kernel_launch(void* const* d_in, const int* in_sizes, int n_in,
                              void* d_out, int out_size, void* d_ws, size_t ws_size,
                              hipStream_t stream) {
    const float* x    = (const float*)d_in[0];
    const float* W_ih = (const float*)d_in[1];
    const float* W_hh = (const float*)d_in[2];
    const float* b_ih = (const float*)d_in[3];
    const float* b_hh = (const float*)d_in[4];
    const float* W_fc = (const float*)d_in[5];
    const float* b_fc = (const float*)d_in[6];
    float* out = (float*)d_out;

    const int B = in_sizes[0] / (T_ * IN_);   // 8192
    dim3 grid(B / BPB_), block(NTHR_);
    hipLaunchKernelGGL(lstm_mfma, grid, block, 0, stream,
                       x, W_ih, W_hh, b_ih, b_hh, W_fc, b_fc, out);
}